// Round 5
// baseline (253.530 us; speedup 1.0000x reference)
//
#include <hip/hip_runtime.h>

// SDGCN fused: per (b,t): S=X·X^T, softmax (diag-shift c_r=||x_r||^2, linear Z),
// A-mask, H=(A*P/Z*c_a)·X, relu(H·W^T)*c_b, LayerNorm, +X residual.
// R5: prepass kernel writes bf16 X (row-major) + bf16 X^T (per bt) + bf16 W into
//     d_ws. Main kernel: QK B-frags direct from global bf16 (L1-shared), PV
//     B-operand staged from pre-transposed XT via trivial coalesced copy into
//     double-buffered LDS -> ONE barrier per chunk, no in-kernel transpose, no
//     per-chunk f2bf. Fallback to R4 kernel if ws_size too small.

#define NNODES 1024
#define DDIM   128
#define MC     64
#define NCHUNK (NNODES / MC)

#define CA 0.08838834764831845f   // 1/sqrt(128+1e-8)
#define CB 0.08838834764831845f   // 1/sqrt(128+1e-9)
#define LN_EPS 1e-5f

typedef __attribute__((ext_vector_type(8))) short bf16x8;
typedef __attribute__((ext_vector_type(4))) float f32x4;
typedef unsigned short ushort_t;

__device__ __forceinline__ unsigned short f2bf(float f) {
  unsigned int u = __float_as_uint(f);
  u += 0x7FFFu + ((u >> 16) & 1u);     // RNE
  return (unsigned short)(u >> 16);
}
__device__ __forceinline__ float bf2f(unsigned short u) {
  return __uint_as_float(((unsigned int)u) << 16);
}

// ============================ PREPASS =====================================
// grid (64 bt, 16 mtiles), 256 thr. Writes Xr (bf16 row-major), XT (bf16
// transposed per bt), Wb (bf16). LDS: Xbf[64][136] @0, XbT[128][72] @8704.
__global__ __launch_bounds__(256, 8)
void sdgcn_prepass(const float* __restrict__ X, const float* __restrict__ W,
                   ushort_t* __restrict__ Xr, ushort_t* __restrict__ XT,
                   ushort_t* __restrict__ Wb) {
  const int bt = blockIdx.x, mt = blockIdx.y, m0 = mt * 64;
  const int tid = (int)threadIdx.x;
  __shared__ __align__(16) ushort_t sm[17920];
  const float* Xs = X + ((size_t)bt * NNODES + m0) * DDIM;
  ushort_t* Xro = Xr + ((size_t)bt * NNODES + m0) * DDIM;
  // phase 1: fp32 -> bf16, to LDS Xbf and global Xr
#pragma unroll
  for (int k = 0; k < 8; ++k) {
    int idx = tid + k * 256;             // 2048 float4 = 64 x 128
    int m = idx >> 5, d4 = idx & 31;
    float4 v = *(const float4*)(Xs + (size_t)m * DDIM + d4 * 4);
    unsigned int lo = (unsigned int)f2bf(v.x) | ((unsigned int)f2bf(v.y) << 16);
    unsigned int hi = (unsigned int)f2bf(v.z) | ((unsigned int)f2bf(v.w) << 16);
    *(uint2*)(sm + m * 136 + d4 * 4) = make_uint2(lo, hi);
    *(uint2*)(Xro + (size_t)m * DDIM + d4 * 4) = make_uint2(lo, hi);
  }
  __syncthreads();
  // phase 2: transpose Xbf -> XbT[128][72] in LDS
#pragma unroll
  for (int k = 0; k < 4; ++k) {
    int task = tid + k * 256;            // 1024 tasks = 128 d x 8 m-octets
    int d = task & 127, m8 = task >> 7;
    int base = d;
    unsigned int w0 = (unsigned int)sm[base + (m8*8+0)*136] | ((unsigned int)sm[base + (m8*8+1)*136] << 16);
    unsigned int w1 = (unsigned int)sm[base + (m8*8+2)*136] | ((unsigned int)sm[base + (m8*8+3)*136] << 16);
    unsigned int w2 = (unsigned int)sm[base + (m8*8+4)*136] | ((unsigned int)sm[base + (m8*8+5)*136] << 16);
    unsigned int w3 = (unsigned int)sm[base + (m8*8+6)*136] | ((unsigned int)sm[base + (m8*8+7)*136] << 16);
    *(uint4*)(sm + 8704 + d * 72 + m8 * 8) = make_uint4(w0, w1, w2, w3);
  }
  __syncthreads();
  // phase 3: XbT -> global XT (coalesced 128B segments)
#pragma unroll
  for (int k = 0; k < 4; ++k) {
    int task = tid + k * 256;            // 1024 tasks = 128 d x 8 segs
    int d = task >> 3, seg = task & 7;
    uint4 w = *(const uint4*)(sm + 8704 + d * 72 + seg * 8);
    *(uint4*)(XT + ((size_t)bt * DDIM + d) * NNODES + m0 + seg * 8) = w;
  }
  // W conversion (4 blocks cover 128x128)
  if (bt == 0 && mt < 4) {
    const float* ws = W + mt * 4096 + tid * 16;
    ushort_t* wd = Wb + mt * 4096 + tid * 16;
#pragma unroll
    for (int k = 0; k < 4; ++k) {
      float4 v = *(const float4*)(ws + k * 4);
      unsigned int lo = (unsigned int)f2bf(v.x) | ((unsigned int)f2bf(v.y) << 16);
      unsigned int hi = (unsigned int)f2bf(v.z) | ((unsigned int)f2bf(v.w) << 16);
      *(uint2*)(wd + k * 4) = make_uint2(lo, hi);
    }
  }
}

// ============================ MAIN (R5) ===================================
// grid (64 bt, 8 rowblocks), 512 thr (8 waves x 16 rows). LDS: XbT dbuf
// 2x9216 + P 8x1152 = 27648 ush = 55296 B -> 2 blocks/CU.
__global__ __launch_bounds__(512, 4)
void sdgcn_main(const float* __restrict__ X, const float* __restrict__ A,
                const float* __restrict__ gamma, const float* __restrict__ beta,
                const ushort_t* __restrict__ Xr, const ushort_t* __restrict__ XT,
                const ushort_t* __restrict__ Wb, float* __restrict__ Out) {
  const int bt   = blockIdx.x;
  const int row0 = blockIdx.y * 128;
  const int tid  = (int)threadIdx.x;
  const int wid  = tid >> 6;
  const int lane = tid & 63;
  const int c    = lane & 15;
  const int q    = lane >> 4;

  const ushort_t* Xrb = Xr + (size_t)bt * NNODES * DDIM;
  const ushort_t* XTb = XT + (size_t)bt * DDIM * NNODES;

  __shared__ __align__(16) ushort_t sm[27648];
  ushort_t* Pw = sm + 18432 + wid * 1152;       // P per wave [16][72]

  const int wswz = 16 * (q >> 1);
  const int rswz = 16 * ((c >> 3) & 1);

  // ---- Q A-fragments (bf16 direct) + row norms (fp32 from bf16: exact shift) ----
  bf16x8 qfrag[4];
  float cn[4];
  {
    const ushort_t* qrow = Xrb + (size_t)(row0 + wid * 16 + c) * DDIM;
    float ss = 0.f;
#pragma unroll
    for (int ds = 0; ds < 4; ++ds) {
      qfrag[ds] = *(const bf16x8*)(qrow + ds * 32 + q * 8);
      union { bf16x8 v; unsigned short u[8]; } t; t.v = qfrag[ds];
#pragma unroll
      for (int j = 0; j < 8; ++j) { float v = bf2f(t.u[j]); ss += v * v; }
    }
    ss += __shfl_xor(ss, 16, 64);
    ss += __shfl_xor(ss, 32, 64);
#pragma unroll
    for (int r = 0; r < 4; ++r)
      cn[r] = __shfl(ss, (lane & 48) + ((lane & 48) >> 2) + r, 64);
  }

  float z_st[4] = {0.f, 0.f, 0.f, 0.f};
  f32x4 Ofr[8];
#pragma unroll
  for (int dt = 0; dt < 8; ++dt) Ofr[dt] = (f32x4){0.f, 0.f, 0.f, 0.f};

  const int grow = row0 + wid * 16 + q * 4;
  const int std_ = tid >> 3, sseg = tid & 7;   // staging task0: d, seg (task1 = +512)

  // ---- stage chunk 0 -> XbT[0] ----
#pragma unroll
  for (int k = 0; k < 2; ++k) {
    int d = std_ + k * 64, seg = sseg;
    *(uint4*)(sm + d * 72 + seg * 8) =
        *(const uint4*)(XTb + (size_t)d * NNODES + seg * 8);
  }

  for (int ch = 0; ch < NCHUNK; ++ch) {
    const int m0 = ch * MC;
    const int cur = (ch & 1) * 9216, nxt = 9216 - cur;
    __syncthreads();   // XbT[cur] staged (prev iter) visible; PV(ch-1) reads done
    // ---- stage chunk ch+1 -> XbT[nxt] (1 b128 load + 1 b128 write x2) ----
    if (ch + 1 < NCHUNK) {
#pragma unroll
      for (int k = 0; k < 2; ++k) {
        int d = std_ + k * 64, seg = sseg;
        *(uint4*)(sm + nxt + d * 72 + seg * 8) =
            *(const uint4*)(XTb + (size_t)d * NNODES + (m0 + MC) + seg * 8);
      }
    }
    // ---- adjacency prefetch (L2-shared across bt-fast blocks) ----
    float av[4][4];
#pragma unroll
    for (int r = 0; r < 4; ++r)
#pragma unroll
      for (int mt = 0; mt < 4; ++mt)
        av[r][mt] = A[(size_t)(grow + r) * NNODES + m0 + mt*16 + c];
    // ---- QK: B-frags direct from global bf16 rows (L1-resident) ----
    f32x4 S[4];
#pragma unroll
    for (int mt = 0; mt < 4; ++mt) {
      f32x4 acc = (f32x4){0.f, 0.f, 0.f, 0.f};
#pragma unroll
      for (int ds = 0; ds < 4; ++ds) {
        bf16x8 bf = *(const bf16x8*)(Xrb + (size_t)(m0 + mt*16 + c) * DDIM + ds*32 + q*8);
        acc = __builtin_amdgcn_mfma_f32_16x16x32_bf16(qfrag[ds], bf, acc, 0, 0, 0);
      }
      S[mt] = acc;
    }
    // ---- p = exp(S - c_r); linear Z; P-write (col-swizzled, per-wave) ----
#pragma unroll
    for (int r = 0; r < 4; ++r) {
      float zr = 0.f;
#pragma unroll
      for (int mt = 0; mt < 4; ++mt) {
        float p = __expf(S[mt][r] - cn[r]);
        zr += p;
        Pw[(q*4 + r) * 72 + (((mt*16) ^ wswz) + c)] = f2bf(p * av[r][mt]);
      }
      z_st[r] += zr;
    }
    // ---- PV: A=P (LDS, same wave), B=XbT[cur] ----
#pragma unroll
    for (int ks = 0; ks < 2; ++ks) {
      bf16x8 pf = *(const bf16x8*)(Pw + c * 72 + ((ks*32 + q*8) ^ rswz));
#pragma unroll
      for (int dt = 0; dt < 8; ++dt) {
        bf16x8 vf = *(const bf16x8*)(sm + cur + (dt*16 + c) * 72 + ks*32 + q*8);
        Ofr[dt] = __builtin_amdgcn_mfma_f32_16x16x32_bf16(pf, vf, Ofr[dt], 0, 0, 0);
      }
    }
  }

  // ---- finalize Z ----
#pragma unroll
  for (int r = 0; r < 4; ++r) {
    float z = z_st[r];
#pragma unroll
    for (int off = 1; off < 16; off <<= 1) z += __shfl_xor(z, off, 64);
    z_st[r] = z;
  }

  __syncthreads();   // reuse LDS for h
  ushort_t* Hw = sm + wid * 2176;               // h per wave [16][136]
#pragma unroll
  for (int r = 0; r < 4; ++r) {
    float rinv = CA / z_st[r];
#pragma unroll
    for (int dt = 0; dt < 8; ++dt)
      Hw[(q*4 + r) * 136 + (((dt*16) ^ wswz) + c)] = f2bf(Ofr[dt][r] * rinv);
  }
  // ---- G = h·W^T (W from prepass bf16) ----
  f32x4 G[8];
#pragma unroll
  for (int jt = 0; jt < 8; ++jt) G[jt] = (f32x4){0.f, 0.f, 0.f, 0.f};
#pragma unroll
  for (int ks = 0; ks < 4; ++ks) {
    bf16x8 hf = *(const bf16x8*)(Hw + c * 136 + ((ks*32 + q*8) ^ rswz));
#pragma unroll
    for (int jt = 0; jt < 8; ++jt) {
      bf16x8 wf = *(const bf16x8*)(Wb + (size_t)(jt*16 + c) * DDIM + ks*32 + q*8);
      G[jt] = __builtin_amdgcn_mfma_f32_16x16x32_bf16(hf, wf, G[jt], 0, 0, 0);
    }
  }
#pragma unroll
  for (int jt = 0; jt < 8; ++jt)
#pragma unroll
    for (int r = 0; r < 4; ++r) G[jt][r] = fmaxf(G[jt][r], 0.f) * CB;
  // ---- LayerNorm + residual + store ----
  const float* Xbt = X + (size_t)bt * NNODES * DDIM;
  float* Obt = Out + (size_t)bt * NNODES * DDIM;
#pragma unroll
  for (int r = 0; r < 4; ++r) {
    float s1 = 0.f, s2 = 0.f;
#pragma unroll
    for (int jt = 0; jt < 8; ++jt) { float v = G[jt][r]; s1 += v; s2 += v * v; }
#pragma unroll
    for (int off = 1; off < 16; off <<= 1) {
      s1 += __shfl_xor(s1, off, 64);
      s2 += __shfl_xor(s2, off, 64);
    }
    float mu = s1 * (1.f / 128.f);
    float va = s2 * (1.f / 128.f) - mu * mu;
    float rs = rsqrtf(va + LN_EPS);
    const float* xr = Xbt + (size_t)(grow + r) * DDIM;
    float* orow = Obt + (size_t)(grow + r) * DDIM;
#pragma unroll
    for (int jt = 0; jt < 8; ++jt) {
      int col = jt * 16 + c;
      orow[col] = (G[jt][r] - mu) * rs * gamma[col] + beta[col] + xr[col];
    }
  }
}

// ======================= FALLBACK (R4, ws too small) ======================
#define XBF_S 136
#define XBT_S 72
#define P_S   72
#define H_S   136
#define XBF_OFF 0
#define XBT_OFF 8704
#define P_OFF   17920
#define SM_TOT  27136

__device__ __forceinline__ bf16x8 pack8(float4 a, float4 b) {
  union { bf16x8 v; unsigned short u[8]; } pk;
  pk.u[0] = f2bf(a.x); pk.u[1] = f2bf(a.y); pk.u[2] = f2bf(a.z); pk.u[3] = f2bf(a.w);
  pk.u[4] = f2bf(b.x); pk.u[5] = f2bf(b.y); pk.u[6] = f2bf(b.z); pk.u[7] = f2bf(b.w);
  return pk.v;
}

__global__ __launch_bounds__(512, 4)
void sdgcn_fallback(const float* __restrict__ X, const float* __restrict__ A,
                    const float* __restrict__ W, const float* __restrict__ gamma,
                    const float* __restrict__ beta, float* __restrict__ Out) {
  const int bt   = blockIdx.x;
  const int row0 = blockIdx.y * 128;
  const int tid  = (int)threadIdx.x;
  const int wid  = tid >> 6;
  const int lane = tid & 63;
  const int c    = lane & 15;
  const int q    = lane >> 4;
  const float* Xbt = X + (size_t)bt * NNODES * DDIM;
  __shared__ __align__(16) unsigned short sm[SM_TOT];
  unsigned short* Pw = sm + P_OFF + wid * (16 * P_S);
  const int wswz = 16 * (q >> 1);
  const int rswz = 16 * ((c >> 3) & 1);
  bf16x8 qfrag[4];
  float cn[4];
  {
    const float* qrow = Xbt + (size_t)(row0 + wid * 16 + c) * DDIM;
    float ss = 0.f;
#pragma unroll
    for (int ds = 0; ds < 4; ++ds) {
      const float* p = qrow + ds * 32 + q * 8;
      float4 a = *(const float4*)p;
      float4 b = *(const float4*)(p + 4);
      ss += a.x*a.x + a.y*a.y + a.z*a.z + a.w*a.w;
      ss += b.x*b.x + b.y*b.y + b.z*b.z + b.w*b.w;
      qfrag[ds] = pack8(a, b);
    }
    ss += __shfl_xor(ss, 16, 64);
    ss += __shfl_xor(ss, 32, 64);
#pragma unroll
    for (int r = 0; r < 4; ++r)
      cn[r] = __shfl(ss, (lane & 48) + ((lane & 48) >> 2) + r, 64);
  }
  float z_st[4] = {0.f, 0.f, 0.f, 0.f};
  f32x4 Ofr[8];
#pragma unroll
  for (int dt = 0; dt < 8; ++dt) Ofr[dt] = (f32x4){0.f, 0.f, 0.f, 0.f};
  const int grow = row0 + wid * 16 + q * 4;
  const int sm_ = tid >> 5, sd4 = tid & 31;
  float4 stg[4];
#pragma unroll
  for (int k = 0; k < 4; ++k)
    stg[k] = *(const float4*)(Xbt + (size_t)(sm_ + k * 16) * DDIM + sd4 * 4);
  for (int ch = 0; ch < NCHUNK; ++ch) {
    const int m0 = ch * MC;
#pragma unroll
    for (int k = 0; k < 4; ++k) {
      float4 v = stg[k];
      unsigned int lo = (unsigned int)f2bf(v.x) | ((unsigned int)f2bf(v.y) << 16);
      unsigned int hi = (unsigned int)f2bf(v.z) | ((unsigned int)f2bf(v.w) << 16);
      *(uint2*)(sm + XBF_OFF + (sm_ + k * 16) * XBF_S + sd4 * 4) = make_uint2(lo, hi);
    }
    __syncthreads();
    if (ch + 1 < NCHUNK) {
      const float* nx = Xbt + (size_t)(m0 + MC) * DDIM;
#pragma unroll
      for (int k = 0; k < 4; ++k)
        stg[k] = *(const float4*)(nx + (size_t)(sm_ + k * 16) * DDIM + sd4 * 4);
    }
    float av[4][4];
#pragma unroll
    for (int r = 0; r < 4; ++r)
#pragma unroll
      for (int mt = 0; mt < 4; ++mt)
        av[r][mt] = A[(size_t)(grow + r) * NNODES + m0 + mt*16 + c];
#pragma unroll
    for (int k = 0; k < 2; ++k) {
      int task = tid + k * 512;
      int d = task & 127, m8 = task >> 7;
      int base = XBF_OFF + d;
      unsigned int w0 = (unsigned int)sm[base + (m8*8+0)*XBF_S] | ((unsigned int)sm[base + (m8*8+1)*XBF_S] << 16);
      unsigned int w1 = (unsigned int)sm[base + (m8*8+2)*XBF_S] | ((unsigned int)sm[base + (m8*8+3)*XBF_S] << 16);
      unsigned int w2 = (unsigned int)sm[base + (m8*8+4)*XBF_S] | ((unsigned int)sm[base + (m8*8+5)*XBF_S] << 16);
      unsigned int w3 = (unsigned int)sm[base + (m8*8+6)*XBF_S] | ((unsigned int)sm[base + (m8*8+7)*XBF_S] << 16);
      *(uint4*)(sm + XBT_OFF + d * XBT_S + m8 * 8) = make_uint4(w0, w1, w2, w3);
    }
    f32x4 S[4];
#pragma unroll
    for (int mt = 0; mt < 4; ++mt) {
      f32x4 acc = (f32x4){0.f, 0.f, 0.f, 0.f};
#pragma unroll
      for (int ds = 0; ds < 4; ++ds) {
        bf16x8 bf = *(const bf16x8*)(sm + XBF_OFF + (mt*16 + c) * XBF_S + ds*32 + q*8);
        acc = __builtin_amdgcn_mfma_f32_16x16x32_bf16(qfrag[ds], bf, acc, 0, 0, 0);
      }
      S[mt] = acc;
    }
    __syncthreads();
#pragma unroll
    for (int r = 0; r < 4; ++r) {
      float zr = 0.f;
#pragma unroll
      for (int mt = 0; mt < 4; ++mt) {
        float p = __expf(S[mt][r] - cn[r]);
        zr += p;
        Pw[(q*4 + r) * P_S + (((mt*16) ^ wswz) + c)] = f2bf(p * av[r][mt]);
      }
      z_st[r] += zr;
    }
#pragma unroll
    for (int ks = 0; ks < 2; ++ks) {
      bf16x8 pf = *(const bf16x8*)(Pw + c * P_S + ((ks*32 + q*8) ^ rswz));
#pragma unroll
      for (int dt = 0; dt < 8; ++dt) {
        bf16x8 vf = *(const bf16x8*)(sm + XBT_OFF + (dt*16 + c) * XBT_S + ks*32 + q*8);
        Ofr[dt] = __builtin_amdgcn_mfma_f32_16x16x32_bf16(pf, vf, Ofr[dt], 0, 0, 0);
      }
    }
  }
#pragma unroll
  for (int r = 0; r < 4; ++r) {
    float z = z_st[r];
#pragma unroll
    for (int off = 1; off < 16; off <<= 1) z += __shfl_xor(z, off, 64);
    z_st[r] = z;
  }
  __syncthreads();
  unsigned short* Hw = sm + XBT_OFF + wid * (16 * H_S);
#pragma unroll
  for (int r = 0; r < 4; ++r) {
    float rinv = CA / z_st[r];
#pragma unroll
    for (int dt = 0; dt < 8; ++dt)
      Hw[(q*4 + r) * H_S + (((dt*16) ^ wswz) + c)] = f2bf(Ofr[dt][r] * rinv);
  }
  f32x4 G[8];
#pragma unroll
  for (int jt = 0; jt < 8; ++jt) G[jt] = (f32x4){0.f, 0.f, 0.f, 0.f};
#pragma unroll
  for (int ks = 0; ks < 4; ++ks) {
    bf16x8 hf = *(const bf16x8*)(Hw + c * H_S + ((ks*32 + q*8) ^ rswz));
#pragma unroll
    for (int jt = 0; jt < 8; ++jt) {
      const float* wr = W + (size_t)(jt*16 + c) * DDIM + ks*32 + q*8;
      float4 a = *(const float4*)wr;
      float4 b = *(const float4*)(wr + 4);
      bf16x8 wf = pack8(a, b);
      G[jt] = __builtin_amdgcn_mfma_f32_16x16x32_bf16(hf, wf, G[jt], 0, 0, 0);
    }
  }
#pragma unroll
  for (int jt = 0; jt < 8; ++jt)
#pragma unroll
    for (int r = 0; r < 4; ++r) G[jt][r] = fmaxf(G[jt][r], 0.f) * CB;
  float* Obt = Out + (size_t)bt * NNODES * DDIM;
#pragma unroll
  for (int r = 0; r < 4; ++r) {
    float s1 = 0.f, s2 = 0.f;
#pragma unroll
    for (int jt = 0; jt < 8; ++jt) { float v = G[jt][r]; s1 += v; s2 += v * v; }
#pragma unroll
    for (int off = 1; off < 16; off <<= 1) {
      s1 += __shfl_xor(s1, off, 64);
      s2 += __shfl_xor(s2, off, 64);
    }
    float mu = s1 * (1.f / 128.f);
    float va = s2 * (1.f / 128.f) - mu * mu;
    float rs = rsqrtf(va + LN_EPS);
    const float* xr = Xbt + (size_t)(grow + r) * DDIM;
    float* orow = Obt + (size_t)(grow + r) * DDIM;
#pragma unroll
    for (int jt = 0; jt < 8; ++jt) {
      int col = jt * 16 + c;
      orow[col] = (G[jt][r] - mu) * rs * gamma[col] + beta[col] + xr[col];
    }
  }
}

extern "C" void kernel_launch(void* const* d_in, const int* in_sizes, int n_in,
                              void* d_out, int out_size, void* d_ws, size_t ws_size,
                              hipStream_t stream) {
  const float* X     = (const float*)d_in[0];
  const float* A     = (const float*)d_in[1];
  const float* W     = (const float*)d_in[2];
  const float* gamma = (const float*)d_in[3];
  const float* beta  = (const float*)d_in[4];
  float* Out = (float*)d_out;

  const size_t XR_ELEMS = (size_t)64 * NNODES * DDIM;      // 8388608
  const size_t NEED = (2 * XR_ELEMS + 16384) * sizeof(unsigned short);
  if (ws_size >= NEED) {
    ushort_t* Xr = (ushort_t*)d_ws;
    ushort_t* XT = Xr + XR_ELEMS;
    ushort_t* Wb = XT + XR_ELEMS;
    hipLaunchKernelGGL(sdgcn_prepass, dim3(64, 16), dim3(256), 0, stream,
                       X, W, Xr, XT, Wb);
    hipLaunchKernelGGL(sdgcn_main, dim3(64, 8), dim3(512), 0, stream,
                       X, A, gamma, beta, Xr, XT, Wb, Out);
  } else {
    hipLaunchKernelGGL(sdgcn_fallback, dim3(64, 8), dim3(512), 0, stream,
                       X, A, W, gamma, beta, Out);
  }
}

// Round 6
// 215.871 us; speedup vs baseline: 1.1745x; 1.1745x over previous
//
#include <hip/hip_runtime.h>

// SDGCN fused: per (b,t): S=X·X^T, softmax (shift c_r=||x_r||^2 via MFMA C-init,
// linear Z), A-mask, H=(A*P/Z*c_a)·X, relu(H·W^T)*c_b, LayerNorm, +X residual.
// R6: 32x32x16 MFMA (2x MAC/LDS-byte vs 16x16x32), 32-row waves, 4-wave blocks
//     (256 thr, 128 rows), R4's proven 2-barrier chunk loop, all LDS patterns
//     <=2-way banked. No prepass (R5 post-mortem: not worth the serial cost).

#define NNODES 1024
#define DDIM   128
#define BROWS  128           // rows per block (4 waves x 32)
#define MC     64            // m-chunk
#define NCHUNK (NNODES / MC)
#define THREADS 256

#define CA 0.08838834764831845f   // 1/sqrt(128+1e-8)
#define CB 0.08838834764831845f   // 1/sqrt(128+1e-9)
#define LN_EPS 1e-5f

typedef __attribute__((ext_vector_type(8)))  short bf16x8;
typedef __attribute__((ext_vector_type(16))) float f32x16;

// LDS layout (ushort units)
#define XBF_S 136                 // Xbf[64][136] bf16 chunk rows (34dw stride: 2-way max)
#define XBT_S 72                  // XbT[128][72] transposed chunk (36dw stride)
#define P_S   72                  // P per wave [32][72]
#define H_S   136                 // h per wave [32][136] epilogue (reuse, wid*4352)
#define XBF_OFF 0                 // 8704 ush
#define XBT_OFF 8704              // 9216 ush
#define P_OFF   17920             // 4*2304 = 9216 ush
#define SM_TOT  27136             // 54272 B -> 2 blocks/CU

__device__ __forceinline__ unsigned short f2bf(float f) {
  unsigned int u = __float_as_uint(f);
  u += 0x7FFFu + ((u >> 16) & 1u);     // RNE
  return (unsigned short)(u >> 16);
}

__device__ __forceinline__ bf16x8 pack8(float4 a, float4 b) {
  union { bf16x8 v; unsigned short u[8]; } pk;
  pk.u[0] = f2bf(a.x); pk.u[1] = f2bf(a.y); pk.u[2] = f2bf(a.z); pk.u[3] = f2bf(a.w);
  pk.u[4] = f2bf(b.x); pk.u[5] = f2bf(b.y); pk.u[6] = f2bf(b.z); pk.u[7] = f2bf(b.w);
  return pk.v;
}

__global__ __launch_bounds__(THREADS, 2)   // 2 waves/SIMD = 2 blocks/CU (LDS-matched)
void sdgcn_fused(const float* __restrict__ X, const float* __restrict__ A,
                 const float* __restrict__ W, const float* __restrict__ gamma,
                 const float* __restrict__ beta, float* __restrict__ Out) {
  const int bt   = blockIdx.x;                 // fast axis: A-slice shared in L2/L3
  const int row0 = blockIdx.y * BROWS;
  const int tid  = (int)threadIdx.x;
  const int wid  = tid >> 6;      // wave 0..3
  const int lane = tid & 63;
  const int i32  = lane & 31;     // 32-dim index within MFMA tile
  const int half = lane >> 5;     // k-group

  const float* Xbt = X + (size_t)bt * NNODES * DDIM;

  __shared__ __align__(16) unsigned short sm[SM_TOT];
  unsigned short* Pw = sm + P_OFF + wid * 2304;

  const int growb = row0 + wid * 32;           // wave's first row

  // ---- Q A-fragments (A[i=i32][k=half*8+j] per 16-kstep) + row norms ----
  bf16x8 qfrag[8];
  float cn[16];    // ||row rr||^2 for this lane's 16 C/D rows (rr below)
  {
    const float* qrow = Xbt + (size_t)(growb + i32) * DDIM;
    float ss = 0.f;
#pragma unroll
    for (int ks = 0; ks < 8; ++ks) {
      const float* p = qrow + ks * 16 + half * 8;
      float4 a = *(const float4*)p;
      float4 b = *(const float4*)(p + 4);
      ss += a.x*a.x + a.y*a.y + a.z*a.z + a.w*a.w;
      ss += b.x*b.x + b.y*b.y + b.z*b.z + b.w*b.w;
      qfrag[ks] = pack8(a, b);
    }
    ss += __shfl_xor(ss, 32, 64);          // lane L now holds ||row (L&31)||^2
#pragma unroll
    for (int r = 0; r < 16; ++r) {
      int rr = (r & 3) + 8 * (r >> 2) + 4 * half;   // C/D row for reg r
      cn[r] = __shfl(ss, rr, 64);
    }
  }

  float z_st[16];
#pragma unroll
  for (int r = 0; r < 16; ++r) z_st[r] = 0.f;
  f32x16 Ofr[4];   // O[32 rows][128 d]: 4 d-tiles, C/D layout
#pragma unroll
  for (int dt = 0; dt < 4; ++dt)
#pragma unroll
    for (int r = 0; r < 16; ++r) Ofr[dt][r] = 0.f;

  // ---- staging: thread covers (m = (tid>>5)+8k, d4 = tid&31), k=0..7 ----
  const int smr = tid >> 5, sd4 = tid & 31;
  float4 stg[8];
#pragma unroll
  for (int k = 0; k < 8; ++k)
    stg[k] = *(const float4*)(Xbt + (size_t)(smr + 8*k) * DDIM + sd4 * 4);

  for (int ch = 0; ch < NCHUNK; ++ch) {
    const int m0 = ch * MC;
    // ---- write staged regs -> Xbf bf16 (uint2: banks 2-way max) ----
#pragma unroll
    for (int k = 0; k < 8; ++k) {
      float4 v = stg[k];
      unsigned int lo = (unsigned int)f2bf(v.x) | ((unsigned int)f2bf(v.y) << 16);
      unsigned int hi = (unsigned int)f2bf(v.z) | ((unsigned int)f2bf(v.w) << 16);
      *(uint2*)(sm + XBF_OFF + (smr + 8*k) * XBF_S + sd4 * 4) = make_uint2(lo, hi);
    }
    __syncthreads();   // B1: Xbf ready; prev-iter PV reads of XbT done
    // ---- issue next chunk's staging loads (full-chunk prefetch distance) ----
    if (ch + 1 < NCHUNK) {
      const float* nx = Xbt + (size_t)(m0 + MC) * DDIM;
#pragma unroll
      for (int k = 0; k < 8; ++k)
        stg[k] = *(const float4*)(nx + (size_t)(smr + 8*k) * DDIM + sd4 * 4);
    }
    // ---- transpose Xbf -> XbT (u16 col reads 2-way, b128 writes) ----
#pragma unroll
    for (int k = 0; k < 4; ++k) {
      int task = tid + k * THREADS;          // 1024 = 128 d x 8 m-octets
      int d = task & 127, m8 = task >> 7;
      int base = XBF_OFF + d;
      unsigned int w0 = (unsigned int)sm[base + (m8*8+0)*XBF_S] | ((unsigned int)sm[base + (m8*8+1)*XBF_S] << 16);
      unsigned int w1 = (unsigned int)sm[base + (m8*8+2)*XBF_S] | ((unsigned int)sm[base + (m8*8+3)*XBF_S] << 16);
      unsigned int w2 = (unsigned int)sm[base + (m8*8+4)*XBF_S] | ((unsigned int)sm[base + (m8*8+5)*XBF_S] << 16);
      unsigned int w3 = (unsigned int)sm[base + (m8*8+6)*XBF_S] | ((unsigned int)sm[base + (m8*8+7)*XBF_S] << 16);
      *(uint4*)(sm + XBT_OFF + d * XBT_S + m8 * 8) = make_uint4(w0, w1, w2, w3);
    }
    // ---- QK: S[32 rows][64 m] = 2 m-tiles of 32x32, C-init = -c_r (free shift) ----
    f32x16 S[2];
#pragma unroll
    for (int mt = 0; mt < 2; ++mt) {
      f32x16 acc;
#pragma unroll
      for (int r = 0; r < 16; ++r) acc[r] = -cn[r];
#pragma unroll
      for (int ks = 0; ks < 8; ++ks) {
        bf16x8 bf = *(const bf16x8*)(sm + XBF_OFF + (mt*32 + i32) * XBF_S + ks*16 + half*8);
        acc = __builtin_amdgcn_mfma_f32_32x32x16_bf16(qfrag[ks], bf, acc, 0, 0, 0);
      }
      S[mt] = acc;
    }
    __syncthreads();   // B2: XbT complete; Xbf free for rewrite next iter
    // ---- adjacency loads (issued as a batch, consumed just below) ----
    float av[16][2];
#pragma unroll
    for (int r = 0; r < 16; ++r) {
      int rr = (r & 3) + 8 * (r >> 2) + 4 * half;
#pragma unroll
      for (int mt = 0; mt < 2; ++mt)
        av[r][mt] = A[(size_t)(growb + rr) * NNODES + m0 + mt*32 + i32];
    }
    // ---- p = exp(S - c_r) (shift already in S); linear Z; P-write (2-way banks) ----
#pragma unroll
    for (int r = 0; r < 16; ++r) {
      int rr = (r & 3) + 8 * (r >> 2) + 4 * half;
#pragma unroll
      for (int mt = 0; mt < 2; ++mt) {
        float p = __expf(S[mt][r]);
        z_st[r] += p;
        Pw[rr * P_S + mt*32 + i32] = f2bf(p * av[r][mt]);
      }
    }
    // ---- PV: O += P·Xchunk; A=P[i=i32][k=m], B=XbT[d=dt*32+i32][k=m] ----
#pragma unroll
    for (int ks = 0; ks < 4; ++ks) {
      bf16x8 pf = *(const bf16x8*)(Pw + i32 * P_S + ks*16 + half*8);
#pragma unroll
      for (int dt = 0; dt < 4; ++dt) {
        bf16x8 vf = *(const bf16x8*)(sm + XBT_OFF + (dt*32 + i32) * XBT_S + ks*16 + half*8);
        Ofr[dt] = __builtin_amdgcn_mfma_f32_32x32x16_bf16(pf, vf, Ofr[dt], 0, 0, 0);
      }
    }
  }

  // ---- finalize Z: sum over 32 cols (within each lane-half) ----
#pragma unroll
  for (int r = 0; r < 16; ++r) {
    float z = z_st[r];
#pragma unroll
    for (int off = 1; off < 32; off <<= 1) z += __shfl_xor(z, off, 64);
    z_st[r] = z;
  }

  __syncthreads();   // all waves done with Xbf/XbT/P; reuse LDS for h
  unsigned short* Hw = sm + wid * (32 * H_S);  // [32][136] per wave
#pragma unroll
  for (int r = 0; r < 16; ++r) {
    int rr = (r & 3) + 8 * (r >> 2) + 4 * half;
    float rinv = CA / z_st[r];
#pragma unroll
    for (int dt = 0; dt < 4; ++dt)
      Hw[rr * H_S + dt*32 + i32] = f2bf(Ofr[dt][r] * rinv);
  }
  // ---- G = h·W^T: A=h from Hw, B=W rows from global (pack to bf16) ----
  f32x16 G[4];
#pragma unroll
  for (int jt = 0; jt < 4; ++jt)
#pragma unroll
    for (int r = 0; r < 16; ++r) G[jt][r] = 0.f;
#pragma unroll
  for (int ks = 0; ks < 8; ++ks) {
    bf16x8 hf = *(const bf16x8*)(Hw + i32 * H_S + ks*16 + half*8);
#pragma unroll
    for (int jt = 0; jt < 4; ++jt) {
      const float* wr = W + (size_t)(jt*32 + i32) * DDIM + ks*16 + half*8;
      float4 a = *(const float4*)wr;
      float4 b = *(const float4*)(wr + 4);
      bf16x8 wf = pack8(a, b);
      G[jt] = __builtin_amdgcn_mfma_f32_32x32x16_bf16(hf, wf, G[jt], 0, 0, 0);
    }
  }
  // relu + output scale
#pragma unroll
  for (int jt = 0; jt < 4; ++jt)
#pragma unroll
    for (int r = 0; r < 16; ++r) G[jt][r] = fmaxf(G[jt][r], 0.f) * CB;
  // ---- LayerNorm over j + residual + store ----
  float gj[4], bj[4];
#pragma unroll
  for (int jt = 0; jt < 4; ++jt) {
    gj[jt] = gamma[jt*32 + i32];
    bj[jt] = beta[jt*32 + i32];
  }
  float* Obt = Out + (size_t)bt * NNODES * DDIM;
#pragma unroll
  for (int r = 0; r < 16; ++r) {
    int rr = (r & 3) + 8 * (r >> 2) + 4 * half;
    float s1 = 0.f, s2 = 0.f;
#pragma unroll
    for (int jt = 0; jt < 4; ++jt) { float v = G[jt][r]; s1 += v; s2 += v * v; }
#pragma unroll
    for (int off = 1; off < 32; off <<= 1) {
      s1 += __shfl_xor(s1, off, 64);
      s2 += __shfl_xor(s2, off, 64);
    }
    float mu = s1 * (1.f / 128.f);
    float va = s2 * (1.f / 128.f) - mu * mu;
    float rs = rsqrtf(va + LN_EPS);
    const float* xr = Xbt + (size_t)(growb + rr) * DDIM;
    float* orow = Obt + (size_t)(growb + rr) * DDIM;
#pragma unroll
    for (int jt = 0; jt < 4; ++jt) {
      int col = jt * 32 + i32;
      orow[col] = (G[jt][r] - mu) * rs * gj[jt] + bj[jt] + xr[col];
    }
  }
}

extern "C" void kernel_launch(void* const* d_in, const int* in_sizes, int n_in,
                              void* d_out, int out_size, void* d_ws, size_t ws_size,
                              hipStream_t stream) {
  const float* X     = (const float*)d_in[0];
  const float* A     = (const float*)d_in[1];
  const float* W     = (const float*)d_in[2];
  const float* gamma = (const float*)d_in[3];
  const float* beta  = (const float*)d_in[4];
  float* Out = (float*)d_out;
  dim3 grid(64, NNODES / BROWS);   // bt fast (A L2 sharing), 8 row-blocks
  hipLaunchKernelGGL(sdgcn_fused, grid, dim3(THREADS), 0, stream, X, A, W, gamma, beta, Out);
}

// Round 7
// 214.671 us; speedup vs baseline: 1.1810x; 1.0056x over previous
//
#include <hip/hip_runtime.h>

// SDGCN fused: per (b,t): S=X·X^T, softmax (shift c_r=||x_r||^2 via MFMA C-init,
// linear Z), A-mask, H=(A*P/Z*c_a)·X, relu(H·W^T)*c_b, LayerNorm, +X residual.
// R7: R6 (32x32x16 MFMA, conflict-free LDS) minus the register spill:
//     staging packed to bf16 on arrival (32->16), A-mask packed bf16 (32->16),
//     S processed per-m-tile (32->16). Arch ~140 + acc ~80 fits 256-reg budget.

#define NNODES 1024
#define DDIM   128
#define BROWS  128           // rows per block (4 waves x 32)
#define MC     64            // m-chunk
#define NCHUNK (NNODES / MC)
#define THREADS 256

#define CA 0.08838834764831845f   // 1/sqrt(128+1e-8)
#define CB 0.08838834764831845f   // 1/sqrt(128+1e-9)
#define LN_EPS 1e-5f

typedef __attribute__((ext_vector_type(8)))  short bf16x8;
typedef __attribute__((ext_vector_type(16))) float f32x16;

// LDS layout (ushort units) — all patterns measured conflict-free in R6
#define XBF_S 136                 // Xbf[64][136] bf16 chunk rows
#define XBT_S 72                  // XbT[128][72] transposed chunk
#define P_S   72                  // P per wave [32][72]
#define H_S   136                 // h per wave [32][136] epilogue (reuse)
#define XBF_OFF 0                 // 8704 ush
#define XBT_OFF 8704              // 9216 ush
#define P_OFF   17920             // 4*2304 = 9216 ush
#define SM_TOT  27136             // 54272 B -> 2 blocks/CU

__device__ __forceinline__ unsigned short f2bf(float f) {
  unsigned int u = __float_as_uint(f);
  u += 0x7FFFu + ((u >> 16) & 1u);     // RNE
  return (unsigned short)(u >> 16);
}
__device__ __forceinline__ float bf2f(unsigned int u16) {
  return __uint_as_float(u16 << 16);
}
__device__ __forceinline__ unsigned int pk2(float x, float y) {
  return (unsigned int)f2bf(x) | ((unsigned int)f2bf(y) << 16);
}

__device__ __forceinline__ bf16x8 pack8(float4 a, float4 b) {
  union { bf16x8 v; unsigned short u[8]; } pk;
  pk.u[0] = f2bf(a.x); pk.u[1] = f2bf(a.y); pk.u[2] = f2bf(a.z); pk.u[3] = f2bf(a.w);
  pk.u[4] = f2bf(b.x); pk.u[5] = f2bf(b.y); pk.u[6] = f2bf(b.z); pk.u[7] = f2bf(b.w);
  return pk.v;
}

__global__ __launch_bounds__(THREADS, 2)   // 2 waves/SIMD = 2 blocks/CU
void sdgcn_fused(const float* __restrict__ X, const float* __restrict__ A,
                 const float* __restrict__ W, const float* __restrict__ gamma,
                 const float* __restrict__ beta, float* __restrict__ Out) {
  const int bt   = blockIdx.x;                 // fast axis: A-slice shared in L2/L3
  const int row0 = blockIdx.y * BROWS;
  const int tid  = (int)threadIdx.x;
  const int wid  = tid >> 6;      // wave 0..3
  const int lane = tid & 63;
  const int i32  = lane & 31;     // 32-dim index within MFMA tile
  const int half = lane >> 5;     // k-group

  const float* Xbt = X + (size_t)bt * NNODES * DDIM;

  __shared__ __align__(16) unsigned short sm[SM_TOT];
  unsigned short* Pw = sm + P_OFF + wid * 2304;

  const int growb = row0 + wid * 32;           // wave's first row

  // ---- Q A-fragments (A[i=i32][k=half*8+j] per 16-kstep) + row norms ----
  bf16x8 qfrag[8];
  float cn[16];    // ||row rr||^2 for this lane's 16 C/D rows
  {
    const float* qrow = Xbt + (size_t)(growb + i32) * DDIM;
    float ss = 0.f;
#pragma unroll
    for (int ks = 0; ks < 8; ++ks) {
      const float* p = qrow + ks * 16 + half * 8;
      float4 a = *(const float4*)p;
      float4 b = *(const float4*)(p + 4);
      ss += a.x*a.x + a.y*a.y + a.z*a.z + a.w*a.w;
      ss += b.x*b.x + b.y*b.y + b.z*b.z + b.w*b.w;
      qfrag[ks] = pack8(a, b);
    }
    ss += __shfl_xor(ss, 32, 64);          // lane L holds ||row (L&31)||^2
#pragma unroll
    for (int r = 0; r < 16; ++r) {
      int rr = (r & 3) + 8 * (r >> 2) + 4 * half;   // C/D row for reg r
      cn[r] = __shfl(ss, rr, 64);
    }
  }

  float z_st[16];
#pragma unroll
  for (int r = 0; r < 16; ++r) z_st[r] = 0.f;
  f32x16 Ofr[4];   // O[32 rows][128 d], C/D layout (AGPR)
#pragma unroll
  for (int dt = 0; dt < 4; ++dt)
#pragma unroll
    for (int r = 0; r < 16; ++r) Ofr[dt][r] = 0.f;

  // ---- staging: thread covers (m = (tid>>5)+8k, d4 = tid&31); packed bf16 ----
  const int smr = tid >> 5, sd4 = tid & 31;
  uint2 stp[8];    // 16 regs (bf16 x4 each)
#pragma unroll
  for (int k = 0; k < 8; ++k) {
    float4 v = *(const float4*)(Xbt + (size_t)(smr + 8*k) * DDIM + sd4 * 4);
    stp[k] = make_uint2(pk2(v.x, v.y), pk2(v.z, v.w));
  }

  for (int ch = 0; ch < NCHUNK; ++ch) {
    const int m0 = ch * MC;
    // ---- write staged packed regs -> Xbf ----
#pragma unroll
    for (int k = 0; k < 8; ++k)
      *(uint2*)(sm + XBF_OFF + (smr + 8*k) * XBF_S + sd4 * 4) = stp[k];
    __syncthreads();   // B1: Xbf ready; prev-iter PV reads of XbT done
    // ---- issue next chunk's staging loads; pack on arrival ----
    if (ch + 1 < NCHUNK) {
      const float* nx = Xbt + (size_t)(m0 + MC) * DDIM;
#pragma unroll
      for (int k = 0; k < 8; ++k) {
        float4 v = *(const float4*)(nx + (size_t)(smr + 8*k) * DDIM + sd4 * 4);
        stp[k] = make_uint2(pk2(v.x, v.y), pk2(v.z, v.w));
      }
    }
    // ---- adjacency loads, packed bf16 pairs (16 regs) ----
    unsigned int av_pk[16];
#pragma unroll
    for (int r = 0; r < 16; ++r) {
      int rr = (r & 3) + 8 * (r >> 2) + 4 * half;
      const float* ar = A + (size_t)(growb + rr) * NNODES + m0 + i32;
      av_pk[r] = pk2(ar[0], ar[32]);
    }
    // ---- transpose Xbf -> XbT (u16 col reads 2-way, b128 writes) ----
#pragma unroll
    for (int k = 0; k < 4; ++k) {
      int task = tid + k * THREADS;          // 1024 = 128 d x 8 m-octets
      int d = task & 127, m8 = task >> 7;
      int base = XBF_OFF + d;
      unsigned int w0 = (unsigned int)sm[base + (m8*8+0)*XBF_S] | ((unsigned int)sm[base + (m8*8+1)*XBF_S] << 16);
      unsigned int w1 = (unsigned int)sm[base + (m8*8+2)*XBF_S] | ((unsigned int)sm[base + (m8*8+3)*XBF_S] << 16);
      unsigned int w2 = (unsigned int)sm[base + (m8*8+4)*XBF_S] | ((unsigned int)sm[base + (m8*8+5)*XBF_S] << 16);
      unsigned int w3 = (unsigned int)sm[base + (m8*8+6)*XBF_S] | ((unsigned int)sm[base + (m8*8+7)*XBF_S] << 16);
      *(uint4*)(sm + XBT_OFF + d * XBT_S + m8 * 8) = make_uint4(w0, w1, w2, w3);
    }
    // ---- QK + softmax numerator per 32x32 m-tile (S reused: 16 regs) ----
#pragma unroll
    for (int mt = 0; mt < 2; ++mt) {
      f32x16 S;
#pragma unroll
      for (int r = 0; r < 16; ++r) S[r] = -cn[r];   // free shift via C-init
#pragma unroll
      for (int ks = 0; ks < 8; ++ks) {
        bf16x8 bf = *(const bf16x8*)(sm + XBF_OFF + (mt*32 + i32) * XBF_S + ks*16 + half*8);
        S = __builtin_amdgcn_mfma_f32_32x32x16_bf16(qfrag[ks], bf, S, 0, 0, 0);
      }
#pragma unroll
      for (int r = 0; r < 16; ++r) {
        int rr = (r & 3) + 8 * (r >> 2) + 4 * half;
        float p = __expf(S[r]);
        z_st[r] += p;
        float a = bf2f((av_pk[r] >> (16 * mt)) & 0xFFFFu);
        Pw[rr * P_S + mt*32 + i32] = f2bf(p * a);
      }
    }
    __syncthreads();   // B2: XbT complete; Xbf free for next staging write
    // ---- PV: O += P·Xchunk; A=P[i=i32][k=m], B=XbT[d=dt*32+i32][k=m] ----
#pragma unroll
    for (int ks = 0; ks < 4; ++ks) {
      bf16x8 pf = *(const bf16x8*)(Pw + i32 * P_S + ks*16 + half*8);
#pragma unroll
      for (int dt = 0; dt < 4; ++dt) {
        bf16x8 vf = *(const bf16x8*)(sm + XBT_OFF + (dt*32 + i32) * XBT_S + ks*16 + half*8);
        Ofr[dt] = __builtin_amdgcn_mfma_f32_32x32x16_bf16(pf, vf, Ofr[dt], 0, 0, 0);
      }
    }
  }

  // ---- finalize Z: sum over 32 cols (within each half) ----
#pragma unroll
  for (int r = 0; r < 16; ++r) {
    float z = z_st[r];
#pragma unroll
    for (int off = 1; off < 32; off <<= 1) z += __shfl_xor(z, off, 64);
    z_st[r] = z;
  }

  __syncthreads();   // all waves done with Xbf/XbT/P; reuse LDS for h
  unsigned short* Hw = sm + wid * (32 * H_S);  // [32][136] per wave
#pragma unroll
  for (int r = 0; r < 16; ++r) {
    int rr = (r & 3) + 8 * (r >> 2) + 4 * half;
    float rinv = CA / z_st[r];
#pragma unroll
    for (int dt = 0; dt < 4; ++dt)
      Hw[rr * H_S + dt*32 + i32] = f2bf(Ofr[dt][r] * rinv);
  }
  // ---- G = h·W^T: A=h from Hw, B=W rows from global (pack to bf16) ----
  f32x16 G[4];
#pragma unroll
  for (int jt = 0; jt < 4; ++jt)
#pragma unroll
    for (int r = 0; r < 16; ++r) G[jt][r] = 0.f;
#pragma unroll
  for (int ks = 0; ks < 8; ++ks) {
    bf16x8 hf = *(const bf16x8*)(Hw + i32 * H_S + ks*16 + half*8);
#pragma unroll
    for (int jt = 0; jt < 4; ++jt) {
      const float* wr = W + (size_t)(jt*32 + i32) * DDIM + ks*16 + half*8;
      float4 a = *(const float4*)wr;
      float4 b = *(const float4*)(wr + 4);
      bf16x8 wf = pack8(a, b);
      G[jt] = __builtin_amdgcn_mfma_f32_32x32x16_bf16(hf, wf, G[jt], 0, 0, 0);
    }
  }
  // relu + output scale
#pragma unroll
  for (int jt = 0; jt < 4; ++jt)
#pragma unroll
    for (int r = 0; r < 16; ++r) G[jt][r] = fmaxf(G[jt][r], 0.f) * CB;
  // ---- LayerNorm over j + residual + store ----
  float gj[4], bj[4];
#pragma unroll
  for (int jt = 0; jt < 4; ++jt) {
    gj[jt] = gamma[jt*32 + i32];
    bj[jt] = beta[jt*32 + i32];
  }
  float* Obt = Out + (size_t)bt * NNODES * DDIM;
#pragma unroll
  for (int r = 0; r < 16; ++r) {
    int rr = (r & 3) + 8 * (r >> 2) + 4 * half;
    float s1 = 0.f, s2 = 0.f;
#pragma unroll
    for (int jt = 0; jt < 4; ++jt) { float v = G[jt][r]; s1 += v; s2 += v * v; }
#pragma unroll
    for (int off = 1; off < 32; off <<= 1) {
      s1 += __shfl_xor(s1, off, 64);
      s2 += __shfl_xor(s2, off, 64);
    }
    float mu = s1 * (1.f / 128.f);
    float va = s2 * (1.f / 128.f) - mu * mu;
    float rs = rsqrtf(va + LN_EPS);
    const float* xr = Xbt + (size_t)(growb + rr) * DDIM;
    float* orow = Obt + (size_t)(growb + rr) * DDIM;
#pragma unroll
    for (int jt = 0; jt < 4; ++jt) {
      int col = jt * 32 + i32;
      orow[col] = (G[jt][r] - mu) * rs * gj[jt] + bj[jt] + xr[col];
    }
  }
}

extern "C" void kernel_launch(void* const* d_in, const int* in_sizes, int n_in,
                              void* d_out, int out_size, void* d_ws, size_t ws_size,
                              hipStream_t stream) {
  const float* X     = (const float*)d_in[0];
  const float* A     = (const float*)d_in[1];
  const float* W     = (const float*)d_in[2];
  const float* gamma = (const float*)d_in[3];
  const float* beta  = (const float*)d_in[4];
  float* Out = (float*)d_out;
  dim3 grid(64, NNODES / BROWS);   // bt fast (A L2 sharing), 8 row-blocks
  hipLaunchKernelGGL(sdgcn_fused, grid, dim3(THREADS), 0, stream, X, A, W, gamma, beta, Out);
}